// Round 4
// baseline (705.219 us; speedup 1.0000x reference)
//
#include <hip/hip_runtime.h>
#include <math.h>

#define B_ 16
#define C_ 256
#define CI_ 128
#define N_ 4096
#define M_ 1024
#define EPS_BN 1e-5f

typedef __attribute__((ext_vector_type(8))) short short8;
typedef __attribute__((ext_vector_type(4))) float float4v;

__device__ __forceinline__ unsigned short f2bf(float f) {
    unsigned int u = __builtin_bit_cast(unsigned int, f);
    u += 0x7fff + ((u >> 16) & 1);
    return (unsigned short)(u >> 16);
}
__device__ __forceinline__ float bf2f(unsigned short h) {
    unsigned int u = ((unsigned int)h) << 16;
    return __builtin_bit_cast(float, u);
}

// ---------------- workspace layout (bytes) ----------------
// wp: wh3[3][128][256] @0, wl3 @196608, wwh[256][128] @393216, wwl @458752
// XH bf16 [B][N][256] @524288 (33.5MB), XL @34078720 (33.5MB)
// Q bf16 [B][N][128] @67633152; PHI @84410368; G @101187584 (16.7MB each)
// KP bf16 [B][M][128] @117964800; VT bf16 [B][128][M] @122159104
// ST fp32[512] @126353408
// aliases: YH=PHI, YL=G (dead after pooling); Y2=XH (dead after k1)
#define OFF_W   ((size_t)0)
#define OFF_XH  ((size_t)524288)
#define OFF_XL  ((size_t)34078720)
#define OFF_Q   ((size_t)67633152)
#define OFF_PHI ((size_t)84410368)
#define OFF_G   ((size_t)101187584)
#define OFF_KP  ((size_t)117964800)
#define OFF_VT  ((size_t)122159104)
#define OFF_ST  ((size_t)126353408)
#define OFF_YH  OFF_PHI
#define OFF_YL  OFF_G
#define OFF_Y2  OFF_XH

// ---------------- kW: split all weights into bf16 hi/lo
__global__ void kW_split(const float* __restrict__ th_w, const float* __restrict__ ph_w,
                         const float* __restrict__ g_w, const float* __restrict__ w_w,
                         unsigned short* __restrict__ wp) {
    int idx = blockIdx.x * 256 + threadIdx.x;   // 131072
    float v;
    unsigned short *dh, *dl;
    if (idx < 98304) {
        int proj = idx >> 15;
        int rc = idx & 32767;
        v = ((proj == 0) ? th_w : (proj == 1) ? ph_w : g_w)[rc];
        dh = wp + idx;
        dl = wp + 98304 + idx;
    } else {
        int j = idx - 98304;    // 0..32767
        v = w_w[j];
        dh = wp + 196608 + j;
        dl = wp + 229376 + j;
    }
    unsigned short h = f2bf(v);
    *dh = h;
    *dl = f2bf(v - bf2f(h));
}

// ---------------- kX: transpose+split x [b][c][n] -> XH/XL [b][n][c] bf16
__global__ __launch_bounds__(256) void kX_transpose(const float* __restrict__ x,
                                                    unsigned short* __restrict__ XH,
                                                    unsigned short* __restrict__ XL) {
    __shared__ float xs[64][65];
    int t = threadIdx.x;
    int nt = blockIdx.x;   // 0..63
    int ct = blockIdx.y;   // 0..3
    int b = blockIdx.z;
    const float* xb = x + (size_t)b * C_ * N_ + (size_t)(ct * 64) * N_ + nt * 64;
#pragma unroll
    for (int r = 0; r < 4; r++) {
        int id = t + 256 * r;
        int c = id >> 4, n4 = (id & 15) * 4;
        *(float4*)&xs[c][n4] = *(const float4*)&xb[(size_t)c * N_ + n4];
    }
    __syncthreads();
#pragma unroll
    for (int r = 0; r < 4; r++) {
        int id = t + 256 * r;
        int n = id >> 4, c4 = (id & 15) * 4;
        unsigned short h[4], l[4];
#pragma unroll
        for (int j = 0; j < 4; j++) {
            float v = xs[c4 + j][n];
            h[j] = f2bf(v);
            l[j] = f2bf(v - bf2f(h[j]));
        }
        size_t off = ((size_t)b * N_ + nt * 64 + n) * 256 + ct * 64 + c4;
        uint2 H = {(unsigned int)h[0] | ((unsigned int)h[1] << 16),
                   (unsigned int)h[2] | ((unsigned int)h[3] << 16)};
        uint2 L = {(unsigned int)l[0] | ((unsigned int)l[1] << 16),
                   (unsigned int)l[2] | ((unsigned int)l[3] << 16)};
        *(uint2*)&XH[off] = H;
        *(uint2*)&XL[off] = L;
    }
}

// ---------------- k1: projection GEMM via split-bf16 MFMA
// D[o][n] per (b,proj): A = w[o][c] hi/lo, B = x^T[n][c] hi/lo, acc fp32.
// WG 4 waves; wave: 32 n (2 nt), 128 o (8 ot), K=256 (8 kc).
__global__ __launch_bounds__(256) void k1_proj(
    const unsigned short* __restrict__ XH, const unsigned short* __restrict__ XL,
    const unsigned short* __restrict__ wp,
    const float* __restrict__ b_th, const float* __restrict__ b_ph,
    const float* __restrict__ b_g,
    unsigned short* __restrict__ outQ, unsigned short* __restrict__ outPHI,
    unsigned short* __restrict__ outG) {
    int t = threadIdx.x;
    int w = t >> 6;
    int lane = t & 63;
    int ln = lane & 15;
    int quad = lane >> 4;
    int ntile = blockIdx.x;   // 0..31
    int b = blockIdx.y;
    int proj = blockIdx.z;
    const unsigned short* wh = wp + proj * 32768;
    const unsigned short* wl = wp + 98304 + proj * 32768;
    const float* bias = (proj == 0) ? b_th : (proj == 1) ? b_ph : b_g;
    unsigned short* out = (proj == 0) ? outQ : (proj == 1) ? outPHI : outG;

    int n0 = ntile * 128 + w * 32;
    const unsigned short* xh = XH + ((size_t)b * N_ + n0) * 256;
    const unsigned short* xl = XL + ((size_t)b * N_ + n0) * 256;

    float4v acc[8][2];
#pragma unroll
    for (int ot = 0; ot < 8; ot++)
#pragma unroll
        for (int nt = 0; nt < 2; nt++) acc[ot][nt] = (float4v){0.f, 0.f, 0.f, 0.f};

#pragma unroll
    for (int kc = 0; kc < 8; kc++) {
        int c0 = kc * 32 + quad * 8;
        short8 bh[2], bl[2];
#pragma unroll
        for (int nt = 0; nt < 2; nt++) {
            bh[nt] = *(const short8*)&xh[(size_t)(nt * 16 + ln) * 256 + c0];
            bl[nt] = *(const short8*)&xl[(size_t)(nt * 16 + ln) * 256 + c0];
        }
#pragma unroll
        for (int ot = 0; ot < 8; ot++) {
            short8 ah = *(const short8*)&wh[(size_t)(ot * 16 + ln) * 256 + c0];
            short8 al = *(const short8*)&wl[(size_t)(ot * 16 + ln) * 256 + c0];
#pragma unroll
            for (int nt = 0; nt < 2; nt++) {
                acc[ot][nt] = __builtin_amdgcn_mfma_f32_16x16x32_bf16(
                    ah, bh[nt], acc[ot][nt], 0, 0, 0);
                acc[ot][nt] = __builtin_amdgcn_mfma_f32_16x16x32_bf16(
                    al, bh[nt], acc[ot][nt], 0, 0, 0);
                acc[ot][nt] = __builtin_amdgcn_mfma_f32_16x16x32_bf16(
                    ah, bl[nt], acc[ot][nt], 0, 0, 0);
            }
        }
    }
#pragma unroll
    for (int ot = 0; ot < 8; ot++) {
        float4 bv = *(const float4*)&bias[ot * 16 + quad * 4];
#pragma unroll
        for (int nt = 0; nt < 2; nt++) {
            int n = n0 + nt * 16 + ln;
            unsigned short* p = out + ((size_t)b * N_ + n) * 128 + ot * 16 + quad * 4;
            unsigned short e0 = f2bf(acc[ot][nt][0] + bv.x);
            unsigned short e1 = f2bf(acc[ot][nt][1] + bv.y);
            unsigned short e2 = f2bf(acc[ot][nt][2] + bv.z);
            unsigned short e3 = f2bf(acc[ot][nt][3] + bv.w);
            uint2 pk = {(unsigned int)e0 | ((unsigned int)e1 << 16),
                        (unsigned int)e2 | ((unsigned int)e3 << 16)};
            *(uint2*)p = pk;
        }
    }
}

// ---------------- k2k: 2x2 maxpool PHI (bf16) -> Kp [b][m][128]
__global__ void k2k_pool(const unsigned short* __restrict__ phiF,
                         unsigned short* __restrict__ Kp) {
    int idx = blockIdx.x * 256 + threadIdx.x;   // 16*1024*16
    int c8 = idx & 15;
    int mp = (idx >> 4) & 1023;
    int b = idx >> 14;
    int hp = mp >> 5, wp = mp & 31;
    int n00 = hp * 128 + wp * 2;
    const unsigned short* base = phiF + (size_t)b * N_ * 128 + c8 * 8;
    uint4 r0 = *(const uint4*)&base[(size_t)n00 * 128];
    uint4 r1 = *(const uint4*)&base[(size_t)(n00 + 1) * 128];
    uint4 r2 = *(const uint4*)&base[(size_t)(n00 + 64) * 128];
    uint4 r3 = *(const uint4*)&base[(size_t)(n00 + 65) * 128];
    const unsigned int* a0 = &r0.x; const unsigned int* a1 = &r1.x;
    const unsigned int* a2 = &r2.x; const unsigned int* a3 = &r3.x;
    unsigned int res[4];
#pragma unroll
    for (int j = 0; j < 4; j++) {
        float vlo = fmaxf(fmaxf(bf2f((unsigned short)(a0[j] & 0xffff)),
                                bf2f((unsigned short)(a1[j] & 0xffff))),
                          fmaxf(bf2f((unsigned short)(a2[j] & 0xffff)),
                                bf2f((unsigned short)(a3[j] & 0xffff))));
        float vhi = fmaxf(fmaxf(bf2f((unsigned short)(a0[j] >> 16)),
                                bf2f((unsigned short)(a1[j] >> 16))),
                          fmaxf(bf2f((unsigned short)(a2[j] >> 16)),
                                bf2f((unsigned short)(a3[j] >> 16))));
        res[j] = (unsigned int)f2bf(vlo) | ((unsigned int)f2bf(vhi) << 16);
    }
    uint4 v = {res[0], res[1], res[2], res[3]};
    *(uint4*)&Kp[((size_t)b * M_ + mp) * 128 + c8 * 8] = v;
}

// ---------------- k2v: 2x2 maxpool G (bf16) + transpose -> Vt [b][128][M]
__global__ __launch_bounds__(256) void k2v_poolT(const unsigned short* __restrict__ gF,
                                                 unsigned short* __restrict__ Vt) {
    __shared__ unsigned short tile[64][136];
    int t = threadIdx.x;
    int mb = blockIdx.x;
    int b = blockIdx.y;
#pragma unroll
    for (int it = 0; it < 4; it++) {
        int idx = t + 256 * it;
        int ml = idx >> 4;
        int c8 = idx & 15;
        int mp = mb * 64 + ml;
        int hp = mp >> 5, wp = mp & 31;
        int n00 = hp * 128 + wp * 2;
        const unsigned short* base = gF + (size_t)b * N_ * 128 + c8 * 8;
        uint4 r0 = *(const uint4*)&base[(size_t)n00 * 128];
        uint4 r1 = *(const uint4*)&base[(size_t)(n00 + 1) * 128];
        uint4 r2 = *(const uint4*)&base[(size_t)(n00 + 64) * 128];
        uint4 r3 = *(const uint4*)&base[(size_t)(n00 + 65) * 128];
        const unsigned int* a0 = &r0.x; const unsigned int* a1 = &r1.x;
        const unsigned int* a2 = &r2.x; const unsigned int* a3 = &r3.x;
#pragma unroll
        for (int j = 0; j < 4; j++) {
            float lo = fmaxf(fmaxf(bf2f((unsigned short)(a0[j] & 0xffff)),
                                   bf2f((unsigned short)(a1[j] & 0xffff))),
                             fmaxf(bf2f((unsigned short)(a2[j] & 0xffff)),
                                   bf2f((unsigned short)(a3[j] & 0xffff))));
            float hi = fmaxf(fmaxf(bf2f((unsigned short)(a0[j] >> 16)),
                                   bf2f((unsigned short)(a1[j] >> 16))),
                             fmaxf(bf2f((unsigned short)(a2[j] >> 16)),
                                   bf2f((unsigned short)(a3[j] >> 16))));
            tile[ml][c8 * 8 + 2 * j] = f2bf(lo);
            tile[ml][c8 * 8 + 2 * j + 1] = f2bf(hi);
        }
    }
    __syncthreads();
#pragma unroll
    for (int it = 0; it < 4; it++) {
        int idx = t + 256 * it;
        int c = idx >> 3;
        int m8 = idx & 7;
        unsigned int pk[4];
#pragma unroll
        for (int j = 0; j < 4; j++) {
            unsigned short lo = tile[m8 * 8 + 2 * j][c];
            unsigned short hi = tile[m8 * 8 + 2 * j + 1][c];
            pk[j] = (unsigned int)lo | ((unsigned int)hi << 16);
        }
        uint4 v = {pk[0], pk[1], pk[2], pk[3]};
        *(uint4*)&Vt[((size_t)b * 128 + c) * M_ + mb * 64 + m8 * 8] = v;
    }
}

// ---------------- k3: bf16 MFMA flash attention; epilogue emits bf16 hi/lo
__global__ __launch_bounds__(256, 2) void k3_attn(
    const unsigned short* __restrict__ Q, const unsigned short* __restrict__ Kp,
    const unsigned short* __restrict__ Vt,
    unsigned short* __restrict__ YH, unsigned short* __restrict__ YL) {
    __shared__ __align__(16) unsigned short Ks[32][136];
    __shared__ __align__(16) unsigned short Vs[128][40];
    __shared__ __align__(16) unsigned short Pt[4][16][40];

    int t = threadIdx.x;
    int w = t >> 6;
    int lane = t & 63;
    int ln = lane & 15;
    int quad = lane >> 4;
    int b = blockIdx.y;
    int qbase_wg = blockIdx.x * 128;

    const unsigned short* qb = Q + ((size_t)b * N_ + qbase_wg + w * 32) * 128;
    short8 qfrag[2][4];
#pragma unroll
    for (int qt = 0; qt < 2; qt++)
#pragma unroll
        for (int dc = 0; dc < 4; dc++)
            qfrag[qt][dc] =
                *(const short8*)&qb[(size_t)(qt * 16 + ln) * 128 + dc * 32 + quad * 8];

    float4v O[2][8];
#pragma unroll
    for (int qt = 0; qt < 2; qt++)
#pragma unroll
        for (int ct = 0; ct < 8; ct++) O[qt][ct] = (float4v){0.f, 0.f, 0.f, 0.f};
    float m_run[2] = {-1e30f, -1e30f};
    float l_run[2] = {0.f, 0.f};

    const unsigned short* kg0 = Kp + (size_t)b * M_ * 128;
    const unsigned short* vg0 = Vt + (size_t)b * 128 * M_;

    for (int kc = 0; kc < 32; kc++) {
        const unsigned short* kg = kg0 + (size_t)kc * 32 * 128;
        const unsigned short* vg = vg0 + kc * 32;
        int i0 = t, i1 = t + 256;
        uint4 gk0 = *(const uint4*)(kg + (size_t)i0 * 8);
        uint4 gk1 = *(const uint4*)(kg + (size_t)i1 * 8);
        uint4 gv0 = *(const uint4*)(vg + (size_t)(i0 >> 2) * M_ + (i0 & 3) * 8);
        uint4 gv1 = *(const uint4*)(vg + (size_t)(i1 >> 2) * M_ + (i1 & 3) * 8);
        __syncthreads();
        *(uint4*)&Ks[i0 >> 4][(i0 & 15) * 8] = gk0;
        *(uint4*)&Ks[i1 >> 4][(i1 & 15) * 8] = gk1;
        *(uint4*)&Vs[i0 >> 2][(i0 & 3) * 8] = gv0;
        *(uint4*)&Vs[i1 >> 2][(i1 & 3) * 8] = gv1;
        __syncthreads();

        short8 vf[8];
#pragma unroll
        for (int ct = 0; ct < 8; ct++)
            vf[ct] = *(const short8*)&Vs[ct * 16 + ln][quad * 8];

        float4v S[2][2];
#pragma unroll
        for (int qt = 0; qt < 2; qt++)
#pragma unroll
            for (int mh = 0; mh < 2; mh++) S[qt][mh] = (float4v){0.f, 0.f, 0.f, 0.f};
#pragma unroll
        for (int dc = 0; dc < 4; dc++) {
#pragma unroll
            for (int mh = 0; mh < 2; mh++) {
                short8 kf = *(const short8*)&Ks[mh * 16 + ln][dc * 32 + quad * 8];
#pragma unroll
                for (int qt = 0; qt < 2; qt++)
                    S[qt][mh] = __builtin_amdgcn_mfma_f32_16x16x32_bf16(
                        kf, qfrag[qt][dc], S[qt][mh], 0, 0, 0);
            }
        }

#pragma unroll
        for (int qt = 0; qt < 2; qt++) {
            float mx = S[qt][0][0];
#pragma unroll
            for (int r = 1; r < 4; r++) mx = fmaxf(mx, S[qt][0][r]);
#pragma unroll
            for (int r = 0; r < 4; r++) mx = fmaxf(mx, S[qt][1][r]);
            mx = fmaxf(mx, __shfl_xor(mx, 16));
            mx = fmaxf(mx, __shfl_xor(mx, 32));
            float nm = fmaxf(m_run[qt], mx);
            float al = __expf(m_run[qt] - nm);
            m_run[qt] = nm;
            float ps = 0.f;
            unsigned int pk[2][2];
#pragma unroll
            for (int mh = 0; mh < 2; mh++) {
                float p0 = __expf(S[qt][mh][0] - nm);
                float p1 = __expf(S[qt][mh][1] - nm);
                float p2 = __expf(S[qt][mh][2] - nm);
                float p3 = __expf(S[qt][mh][3] - nm);
                ps += p0 + p1 + p2 + p3;
                pk[mh][0] = (unsigned int)f2bf(p0) | ((unsigned int)f2bf(p1) << 16);
                pk[mh][1] = (unsigned int)f2bf(p2) | ((unsigned int)f2bf(p3) << 16);
            }
            ps += __shfl_xor(ps, 16);
            ps += __shfl_xor(ps, 32);
            l_run[qt] = l_run[qt] * al + ps;
#pragma unroll
            for (int mh = 0; mh < 2; mh++) {
                uint2 wv = {pk[mh][0], pk[mh][1]};
                *(uint2*)&Pt[w][ln][mh * 16 + quad * 4] = wv;
            }
            if (__any(al < 1.0f)) {
#pragma unroll
                for (int ct = 0; ct < 8; ct++)
#pragma unroll
                    for (int r = 0; r < 4; r++) O[qt][ct][r] *= al;
            }
            short8 pf = *(const short8*)&Pt[w][ln][quad * 8];
#pragma unroll
            for (int ct = 0; ct < 8; ct++)
                O[qt][ct] = __builtin_amdgcn_mfma_f32_16x16x32_bf16(
                    vf[ct], pf, O[qt][ct], 0, 0, 0);
        }
    }

#pragma unroll
    for (int qt = 0; qt < 2; qt++) {
        float inv = 1.0f / l_run[qt];
        size_t rowoff = ((size_t)b * N_ + qbase_wg + w * 32 + qt * 16 + ln) * 128;
        unsigned short* yh = YH + rowoff;
        unsigned short* yl = YL + rowoff;
#pragma unroll
        for (int ct = 0; ct < 8; ct++) {
            unsigned short h[4], l[4];
#pragma unroll
            for (int r = 0; r < 4; r++) {
                float v = O[qt][ct][r] * inv;
                h[r] = f2bf(v);
                l[r] = f2bf(v - bf2f(h[r]));
            }
            uint2 H = {(unsigned int)h[0] | ((unsigned int)h[1] << 16),
                       (unsigned int)h[2] | ((unsigned int)h[3] << 16)};
            uint2 L = {(unsigned int)l[0] | ((unsigned int)l[1] << 16),
                       (unsigned int)l[2] | ((unsigned int)l[3] << 16)};
            *(uint2*)&yh[ct * 16 + quad * 4] = H;
            *(uint2*)&yl[ct * 16 + quad * 4] = L;
        }
    }
}

// ---------------- k4: W-conv via split-bf16 MFMA + BN stats
// D[o][n] per b: A = w_w[o][ci] hi/lo, B = Y[n][ci] hi/lo. Wave: 32 n, 256 o.
__global__ __launch_bounds__(256) void k4_convw(
    const unsigned short* __restrict__ YH, const unsigned short* __restrict__ YL,
    const unsigned short* __restrict__ wp, const float* __restrict__ wb,
    unsigned short* __restrict__ Y2, float* __restrict__ stats) {
    int t = threadIdx.x;
    int w = t >> 6;
    int lane = t & 63;
    int ln = lane & 15;
    int quad = lane >> 4;
    int ntile = blockIdx.x;   // 0..31
    int b = blockIdx.y;
    const unsigned short* wwh = wp + 196608;
    const unsigned short* wwl = wp + 229376;

    int n0 = ntile * 128 + w * 32;
    const unsigned short* yh = YH + ((size_t)b * N_ + n0) * 128;
    const unsigned short* yl = YL + ((size_t)b * N_ + n0) * 128;

    float4v acc[16][2];
#pragma unroll
    for (int ot = 0; ot < 16; ot++)
#pragma unroll
        for (int nt = 0; nt < 2; nt++) acc[ot][nt] = (float4v){0.f, 0.f, 0.f, 0.f};

#pragma unroll
    for (int kc = 0; kc < 4; kc++) {
        int c0 = kc * 32 + quad * 8;
        short8 bh[2], bl[2];
#pragma unroll
        for (int nt = 0; nt < 2; nt++) {
            bh[nt] = *(const short8*)&yh[(size_t)(nt * 16 + ln) * 128 + c0];
            bl[nt] = *(const short8*)&yl[(size_t)(nt * 16 + ln) * 128 + c0];
        }
#pragma unroll
        for (int ot = 0; ot < 16; ot++) {
            short8 ah = *(const short8*)&wwh[(size_t)(ot * 16 + ln) * 128 + c0];
            short8 al = *(const short8*)&wwl[(size_t)(ot * 16 + ln) * 128 + c0];
#pragma unroll
            for (int nt = 0; nt < 2; nt++) {
                acc[ot][nt] = __builtin_amdgcn_mfma_f32_16x16x32_bf16(
                    ah, bh[nt], acc[ot][nt], 0, 0, 0);
                acc[ot][nt] = __builtin_amdgcn_mfma_f32_16x16x32_bf16(
                    al, bh[nt], acc[ot][nt], 0, 0, 0);
                acc[ot][nt] = __builtin_amdgcn_mfma_f32_16x16x32_bf16(
                    ah, bl[nt], acc[ot][nt], 0, 0, 0);
            }
        }
    }

#pragma unroll
    for (int ot = 0; ot < 16; ot++) {
        float4 bv = *(const float4*)&wb[ot * 16 + quad * 4];
        float s1[4] = {0.f, 0.f, 0.f, 0.f};
        float s2[4] = {0.f, 0.f, 0.f, 0.f};
#pragma unroll
        for (int nt = 0; nt < 2; nt++) {
#pragma unroll
            for (int r = 0; r < 4; r++) {
                float v = acc[ot][nt][r] + ((const float*)&bv)[r];
                acc[ot][nt][r] = v;
                s1[r] += v;
                s2[r] += v * v;
            }
        }
#pragma unroll
        for (int d = 1; d < 16; d <<= 1) {
#pragma unroll
            for (int r = 0; r < 4; r++) {
                s1[r] += __shfl_xor(s1[r], d);
                s2[r] += __shfl_xor(s2[r], d);
            }
        }
        if (ln == 0) {
#pragma unroll
            for (int r = 0; r < 4; r++) {
                int o = ot * 16 + quad * 4 + r;
                atomicAdd(&stats[o], s1[r]);
                atomicAdd(&stats[256 + o], s2[r]);
            }
        }
#pragma unroll
        for (int nt = 0; nt < 2; nt++) {
            int n = n0 + nt * 16 + ln;
#pragma unroll
            for (int r = 0; r < 4; r++) {
                int o = ot * 16 + quad * 4 + r;
                Y2[((size_t)b * C_ + o) * N_ + n] = f2bf(acc[ot][nt][r]);
            }
        }
    }
}

// ---------------- k6: BN + affine + residual (Y2 bf16 in, fp32 out)
__global__ void k6_bn(const unsigned short* __restrict__ Y2,
                      const float* __restrict__ x,
                      const float* __restrict__ stats,
                      const float* __restrict__ gamma, const float* __restrict__ beta,
                      float* __restrict__ outp) {
    int idx = blockIdx.x * 256 + threadIdx.x;
    size_t base = (size_t)idx * 8;
    int o = (int)((base >> 12) & 255);
    const float cnt = (float)(B_ * N_);
    float mean = stats[o] / cnt;
    float var = stats[256 + o] / cnt - mean * mean;
    float scale = gamma[o] * rsqrtf(var + EPS_BN);
    float shift = beta[o] - mean * scale;
    uint4 yv = *(const uint4*)&Y2[base];
    const unsigned int* yw = &yv.x;
    float4 x0 = *(const float4*)&x[base];
    float4 x1 = *(const float4*)&x[base + 4];
    float y[8];
#pragma unroll
    for (int j = 0; j < 4; j++) {
        y[2 * j] = bf2f((unsigned short)(yw[j] & 0xffff));
        y[2 * j + 1] = bf2f((unsigned short)(yw[j] >> 16));
    }
    float4 o0 = {y[0] * scale + shift + x0.x, y[1] * scale + shift + x0.y,
                 y[2] * scale + shift + x0.z, y[3] * scale + shift + x0.w};
    float4 o1 = {y[4] * scale + shift + x1.x, y[5] * scale + shift + x1.y,
                 y[6] * scale + shift + x1.z, y[7] * scale + shift + x1.w};
    *(float4*)&outp[base] = o0;
    *(float4*)&outp[base + 4] = o1;
}

extern "C" void kernel_launch(void* const* d_in, const int* in_sizes, int n_in,
                              void* d_out, int out_size, void* d_ws, size_t ws_size,
                              hipStream_t stream) {
    const float* x    = (const float*)d_in[0];
    const float* g_w  = (const float*)d_in[1];
    const float* g_b  = (const float*)d_in[2];
    const float* th_w = (const float*)d_in[3];
    const float* th_b = (const float*)d_in[4];
    const float* ph_w = (const float*)d_in[5];
    const float* ph_b = (const float*)d_in[6];
    const float* w_w  = (const float*)d_in[7];
    const float* w_b  = (const float*)d_in[8];
    const float* gam  = (const float*)d_in[9];
    const float* bet  = (const float*)d_in[10];

    char* ws = (char*)d_ws;
    unsigned short* wp  = (unsigned short*)(ws + OFF_W);
    unsigned short* XH  = (unsigned short*)(ws + OFF_XH);
    unsigned short* XL  = (unsigned short*)(ws + OFF_XL);
    unsigned short* Qb  = (unsigned short*)(ws + OFF_Q);
    unsigned short* PHI = (unsigned short*)(ws + OFF_PHI);
    unsigned short* Gb  = (unsigned short*)(ws + OFF_G);
    unsigned short* Kp  = (unsigned short*)(ws + OFF_KP);
    unsigned short* Vt  = (unsigned short*)(ws + OFF_VT);
    unsigned short* YHp = (unsigned short*)(ws + OFF_YH);
    unsigned short* YLp = (unsigned short*)(ws + OFF_YL);
    unsigned short* Y2  = (unsigned short*)(ws + OFF_Y2);
    float*          ST  = (float*)(ws + OFF_ST);
    float* outp = (float*)d_out;

    hipMemsetAsync(ST, 0, 512 * sizeof(float), stream);
    kW_split<<<512, 256, 0, stream>>>(th_w, ph_w, g_w, w_w, wp);
    kX_transpose<<<dim3(64, 4, 16), 256, 0, stream>>>(x, XH, XL);
    k1_proj<<<dim3(32, 16, 3), 256, 0, stream>>>(XH, XL, wp, th_b, ph_b, g_b,
                                                 Qb, PHI, Gb);
    k2k_pool<<<1024, 256, 0, stream>>>(PHI, Kp);
    k2v_poolT<<<dim3(16, 16), 256, 0, stream>>>(Gb, Vt);
    k3_attn<<<dim3(32, 16), 256, 0, stream>>>(Qb, Kp, Vt, YHp, YLp);
    k4_convw<<<dim3(32, 16), 256, 0, stream>>>(YHp, YLp, wp, w_b, Y2, ST);
    k6_bn<<<8192, 256, 0, stream>>>(Y2, x, ST, gam, bet, outp);
}

// Round 5
// 426.655 us; speedup vs baseline: 1.6529x; 1.6529x over previous
//
#include <hip/hip_runtime.h>
#include <math.h>

#define B_ 16
#define C_ 256
#define CI_ 128
#define N_ 4096
#define M_ 1024
#define EPS_BN 1e-5f

typedef __attribute__((ext_vector_type(8))) short short8;
typedef __attribute__((ext_vector_type(4))) float float4v;

__device__ __forceinline__ unsigned short f2bf(float f) {
    unsigned int u = __builtin_bit_cast(unsigned int, f);
    u += 0x7fff + ((u >> 16) & 1);
    return (unsigned short)(u >> 16);
}
__device__ __forceinline__ float bf2f(unsigned short h) {
    unsigned int u = ((unsigned int)h) << 16;
    return __builtin_bit_cast(float, u);
}

// ---------------- workspace layout (bytes) ----------------
#define OFF_W   ((size_t)0)
#define OFF_XH  ((size_t)524288)
#define OFF_XL  ((size_t)34078720)
#define OFF_Q   ((size_t)67633152)
#define OFF_PHI ((size_t)84410368)
#define OFF_G   ((size_t)101187584)
#define OFF_KP  ((size_t)117964800)
#define OFF_VT  ((size_t)122159104)
#define OFF_ST  ((size_t)126353408)
#define OFF_YH  OFF_PHI
#define OFF_YL  OFF_G
#define OFF_Y2  OFF_XH

// ---------------- kW: split all weights into bf16 hi/lo
__global__ void kW_split(const float* __restrict__ th_w, const float* __restrict__ ph_w,
                         const float* __restrict__ g_w, const float* __restrict__ w_w,
                         unsigned short* __restrict__ wp) {
    int idx = blockIdx.x * 256 + threadIdx.x;   // 131072
    float v;
    unsigned short *dh, *dl;
    if (idx < 98304) {
        int proj = idx >> 15;
        int rc = idx & 32767;
        v = ((proj == 0) ? th_w : (proj == 1) ? ph_w : g_w)[rc];
        dh = wp + idx;
        dl = wp + 98304 + idx;
    } else {
        int j = idx - 98304;
        v = w_w[j];
        dh = wp + 196608 + j;
        dl = wp + 229376 + j;
    }
    unsigned short h = f2bf(v);
    *dh = h;
    *dl = f2bf(v - bf2f(h));
}

// ---------------- kX: transpose+split x [b][c][n] -> XH/XL [b][n][c] bf16
__global__ __launch_bounds__(256) void kX_transpose(const float* __restrict__ x,
                                                    unsigned short* __restrict__ XH,
                                                    unsigned short* __restrict__ XL) {
    __shared__ float xs[64][65];
    int t = threadIdx.x;
    int nt = blockIdx.x;
    int ct = blockIdx.y;
    int b = blockIdx.z;
    const float* xb = x + (size_t)b * C_ * N_ + (size_t)(ct * 64) * N_ + nt * 64;
#pragma unroll
    for (int r = 0; r < 4; r++) {
        int id = t + 256 * r;
        int c = id >> 4, n4 = (id & 15) * 4;
        *(float4*)&xs[c][n4] = *(const float4*)&xb[(size_t)c * N_ + n4];
    }
    __syncthreads();
#pragma unroll
    for (int r = 0; r < 4; r++) {
        int id = t + 256 * r;
        int n = id >> 4, c4 = (id & 15) * 4;
        unsigned short h[4], l[4];
#pragma unroll
        for (int j = 0; j < 4; j++) {
            float v = xs[c4 + j][n];
            h[j] = f2bf(v);
            l[j] = f2bf(v - bf2f(h[j]));
        }
        size_t off = ((size_t)b * N_ + nt * 64 + n) * 256 + ct * 64 + c4;
        uint2 H = {(unsigned int)h[0] | ((unsigned int)h[1] << 16),
                   (unsigned int)h[2] | ((unsigned int)h[3] << 16)};
        uint2 L = {(unsigned int)l[0] | ((unsigned int)l[1] << 16),
                   (unsigned int)l[2] | ((unsigned int)l[3] << 16)};
        *(uint2*)&XH[off] = H;
        *(uint2*)&XL[off] = L;
    }
}

// ---------------- k1: projection GEMM, split-bf16 MFMA, LDS-staged weights
__global__ __launch_bounds__(256) void k1_proj(
    const unsigned short* __restrict__ XH, const unsigned short* __restrict__ XL,
    const unsigned short* __restrict__ wp,
    const float* __restrict__ b_th, const float* __restrict__ b_ph,
    const float* __restrict__ b_g,
    unsigned short* __restrict__ outQ, unsigned short* __restrict__ outPHI,
    unsigned short* __restrict__ outG) {
    __shared__ __align__(16) unsigned short lds1[33792];
    unsigned short* Ah = lds1;              // [64][264]
    unsigned short* Al = lds1 + 16896;      // [64][264]
    unsigned short* T  = lds1;              // [256][68] (union, after K-loop)

    int t = threadIdx.x;
    int w = t >> 6;
    int lane = t & 63;
    int ln = lane & 15;
    int quad = lane >> 4;
    int nx = blockIdx.x;
    int oy = blockIdx.y;
    int z = blockIdx.z;
    int proj = z >> 4;
    int b = z & 15;

    const unsigned short* whg = wp + proj * 32768 + oy * 64 * 256;
    const unsigned short* wlg = wp + 98304 + proj * 32768 + oy * 64 * 256;
#pragma unroll
    for (int r2 = 0; r2 < 8; r2++) {
        int i = t + 256 * r2;
        int row = i >> 5, col8 = (i & 31) * 8;
        *(uint4*)&Ah[row * 264 + col8] = *(const uint4*)&whg[row * 256 + col8];
        *(uint4*)&Al[row * 264 + col8] = *(const uint4*)&wlg[row * 256 + col8];
    }
    __syncthreads();

    int n0 = nx * 256 + w * 64;
    const unsigned short* xh = XH + ((size_t)b * N_ + n0) * 256;
    const unsigned short* xl = XL + ((size_t)b * N_ + n0) * 256;

    float4v acc[4][4];
#pragma unroll
    for (int ot = 0; ot < 4; ot++)
#pragma unroll
        for (int nt = 0; nt < 4; nt++) acc[ot][nt] = (float4v){0.f, 0.f, 0.f, 0.f};

#pragma unroll
    for (int kc = 0; kc < 8; kc++) {
        int c0 = kc * 32 + quad * 8;
        short8 bh[4], bl[4];
#pragma unroll
        for (int nt = 0; nt < 4; nt++) {
            bh[nt] = *(const short8*)&xh[(size_t)(nt * 16 + ln) * 256 + c0];
            bl[nt] = *(const short8*)&xl[(size_t)(nt * 16 + ln) * 256 + c0];
        }
#pragma unroll
        for (int ot = 0; ot < 4; ot++) {
            short8 ah = *(const short8*)&Ah[(ot * 16 + ln) * 264 + c0];
            short8 al = *(const short8*)&Al[(ot * 16 + ln) * 264 + c0];
#pragma unroll
            for (int nt = 0; nt < 4; nt++) {
                acc[ot][nt] = __builtin_amdgcn_mfma_f32_16x16x32_bf16(
                    ah, bh[nt], acc[ot][nt], 0, 0, 0);
                acc[ot][nt] = __builtin_amdgcn_mfma_f32_16x16x32_bf16(
                    al, bh[nt], acc[ot][nt], 0, 0, 0);
                acc[ot][nt] = __builtin_amdgcn_mfma_f32_16x16x32_bf16(
                    ah, bl[nt], acc[ot][nt], 0, 0, 0);
            }
        }
    }

    const float* bias = (proj == 0) ? b_th : (proj == 1) ? b_ph : b_g;
    __syncthreads();
#pragma unroll
    for (int ot = 0; ot < 4; ot++) {
        float4 bv = *(const float4*)&bias[oy * 64 + ot * 16 + quad * 4];
#pragma unroll
        for (int nt = 0; nt < 4; nt++)
#pragma unroll
            for (int r = 0; r < 4; r++) {
                float v = acc[ot][nt][r] + ((const float*)&bv)[r];
                T[(w * 64 + nt * 16 + ln) * 68 + ot * 16 + quad * 4 + r] = f2bf(v);
            }
    }
    __syncthreads();

    unsigned short* out = (proj == 0) ? outQ : (proj == 1) ? outPHI : outG;
    unsigned short* ob = out + ((size_t)b * N_ + nx * 256 + t) * 128 + oy * 64;
#pragma unroll
    for (int j = 0; j < 8; j++) {
        uint2 lo = *(uint2*)&T[t * 68 + j * 8];
        uint2 hi = *(uint2*)&T[t * 68 + j * 8 + 4];
        uint4 v = {lo.x, lo.y, hi.x, hi.y};
        *(uint4*)&ob[j * 8] = v;
    }
}

// ---------------- k2k: 2x2 maxpool PHI (bf16) -> Kp [b][m][128]
__global__ void k2k_pool(const unsigned short* __restrict__ phiF,
                         unsigned short* __restrict__ Kp) {
    int idx = blockIdx.x * 256 + threadIdx.x;
    int c8 = idx & 15;
    int mp = (idx >> 4) & 1023;
    int b = idx >> 14;
    int hp = mp >> 5, wp = mp & 31;
    int n00 = hp * 128 + wp * 2;
    const unsigned short* base = phiF + (size_t)b * N_ * 128 + c8 * 8;
    uint4 r0 = *(const uint4*)&base[(size_t)n00 * 128];
    uint4 r1 = *(const uint4*)&base[(size_t)(n00 + 1) * 128];
    uint4 r2 = *(const uint4*)&base[(size_t)(n00 + 64) * 128];
    uint4 r3 = *(const uint4*)&base[(size_t)(n00 + 65) * 128];
    const unsigned int* a0 = &r0.x; const unsigned int* a1 = &r1.x;
    const unsigned int* a2 = &r2.x; const unsigned int* a3 = &r3.x;
    unsigned int res[4];
#pragma unroll
    for (int j = 0; j < 4; j++) {
        float vlo = fmaxf(fmaxf(bf2f((unsigned short)(a0[j] & 0xffff)),
                                bf2f((unsigned short)(a1[j] & 0xffff))),
                          fmaxf(bf2f((unsigned short)(a2[j] & 0xffff)),
                                bf2f((unsigned short)(a3[j] & 0xffff))));
        float vhi = fmaxf(fmaxf(bf2f((unsigned short)(a0[j] >> 16)),
                                bf2f((unsigned short)(a1[j] >> 16))),
                          fmaxf(bf2f((unsigned short)(a2[j] >> 16)),
                                bf2f((unsigned short)(a3[j] >> 16))));
        res[j] = (unsigned int)f2bf(vlo) | ((unsigned int)f2bf(vhi) << 16);
    }
    uint4 v = {res[0], res[1], res[2], res[3]};
    *(uint4*)&Kp[((size_t)b * M_ + mp) * 128 + c8 * 8] = v;
}

// ---------------- k2v: 2x2 maxpool G (bf16) + transpose -> Vt [b][128][M]
__global__ __launch_bounds__(256) void k2v_poolT(const unsigned short* __restrict__ gF,
                                                 unsigned short* __restrict__ Vt) {
    __shared__ unsigned short tile[64][136];
    int t = threadIdx.x;
    int mb = blockIdx.x;
    int b = blockIdx.y;
#pragma unroll
    for (int it = 0; it < 4; it++) {
        int idx = t + 256 * it;
        int ml = idx >> 4;
        int c8 = idx & 15;
        int mp = mb * 64 + ml;
        int hp = mp >> 5, wp = mp & 31;
        int n00 = hp * 128 + wp * 2;
        const unsigned short* base = gF + (size_t)b * N_ * 128 + c8 * 8;
        uint4 r0 = *(const uint4*)&base[(size_t)n00 * 128];
        uint4 r1 = *(const uint4*)&base[(size_t)(n00 + 1) * 128];
        uint4 r2 = *(const uint4*)&base[(size_t)(n00 + 64) * 128];
        uint4 r3 = *(const uint4*)&base[(size_t)(n00 + 65) * 128];
        const unsigned int* a0 = &r0.x; const unsigned int* a1 = &r1.x;
        const unsigned int* a2 = &r2.x; const unsigned int* a3 = &r3.x;
#pragma unroll
        for (int j = 0; j < 4; j++) {
            float lo = fmaxf(fmaxf(bf2f((unsigned short)(a0[j] & 0xffff)),
                                   bf2f((unsigned short)(a1[j] & 0xffff))),
                             fmaxf(bf2f((unsigned short)(a2[j] & 0xffff)),
                                   bf2f((unsigned short)(a3[j] & 0xffff))));
            float hi = fmaxf(fmaxf(bf2f((unsigned short)(a0[j] >> 16)),
                                   bf2f((unsigned short)(a1[j] >> 16))),
                             fmaxf(bf2f((unsigned short)(a2[j] >> 16)),
                                   bf2f((unsigned short)(a3[j] >> 16))));
            tile[ml][c8 * 8 + 2 * j] = f2bf(lo);
            tile[ml][c8 * 8 + 2 * j + 1] = f2bf(hi);
        }
    }
    __syncthreads();
#pragma unroll
    for (int it = 0; it < 4; it++) {
        int idx = t + 256 * it;
        int c = idx >> 3;
        int m8 = idx & 7;
        unsigned int pk[4];
#pragma unroll
        for (int j = 0; j < 4; j++) {
            unsigned short lo = tile[m8 * 8 + 2 * j][c];
            unsigned short hi = tile[m8 * 8 + 2 * j + 1][c];
            pk[j] = (unsigned int)lo | ((unsigned int)hi << 16);
        }
        uint4 v = {pk[0], pk[1], pk[2], pk[3]};
        *(uint4*)&Vt[((size_t)b * 128 + c) * M_ + mb * 64 + m8 * 8] = v;
    }
}

// ---------------- k3: bf16 MFMA flash attention; epilogue emits bf16 hi/lo
__global__ __launch_bounds__(256, 2) void k3_attn(
    const unsigned short* __restrict__ Q, const unsigned short* __restrict__ Kp,
    const unsigned short* __restrict__ Vt,
    unsigned short* __restrict__ YH, unsigned short* __restrict__ YL) {
    __shared__ __align__(16) unsigned short Ks[32][136];
    __shared__ __align__(16) unsigned short Vs[128][40];
    __shared__ __align__(16) unsigned short Pt[4][16][40];

    int t = threadIdx.x;
    int w = t >> 6;
    int lane = t & 63;
    int ln = lane & 15;
    int quad = lane >> 4;
    int b = blockIdx.y;
    int qbase_wg = blockIdx.x * 128;

    const unsigned short* qb = Q + ((size_t)b * N_ + qbase_wg + w * 32) * 128;
    short8 qfrag[2][4];
#pragma unroll
    for (int qt = 0; qt < 2; qt++)
#pragma unroll
        for (int dc = 0; dc < 4; dc++)
            qfrag[qt][dc] =
                *(const short8*)&qb[(size_t)(qt * 16 + ln) * 128 + dc * 32 + quad * 8];

    float4v O[2][8];
#pragma unroll
    for (int qt = 0; qt < 2; qt++)
#pragma unroll
        for (int ct = 0; ct < 8; ct++) O[qt][ct] = (float4v){0.f, 0.f, 0.f, 0.f};
    float m_run[2] = {-1e30f, -1e30f};
    float l_run[2] = {0.f, 0.f};

    const unsigned short* kg0 = Kp + (size_t)b * M_ * 128;
    const unsigned short* vg0 = Vt + (size_t)b * 128 * M_;

    for (int kc = 0; kc < 32; kc++) {
        const unsigned short* kg = kg0 + (size_t)kc * 32 * 128;
        const unsigned short* vg = vg0 + kc * 32;
        int i0 = t, i1 = t + 256;
        uint4 gk0 = *(const uint4*)(kg + (size_t)i0 * 8);
        uint4 gk1 = *(const uint4*)(kg + (size_t)i1 * 8);
        uint4 gv0 = *(const uint4*)(vg + (size_t)(i0 >> 2) * M_ + (i0 & 3) * 8);
        uint4 gv1 = *(const uint4*)(vg + (size_t)(i1 >> 2) * M_ + (i1 & 3) * 8);
        __syncthreads();
        *(uint4*)&Ks[i0 >> 4][(i0 & 15) * 8] = gk0;
        *(uint4*)&Ks[i1 >> 4][(i1 & 15) * 8] = gk1;
        *(uint4*)&Vs[i0 >> 2][(i0 & 3) * 8] = gv0;
        *(uint4*)&Vs[i1 >> 2][(i1 & 3) * 8] = gv1;
        __syncthreads();

        short8 vf[8];
#pragma unroll
        for (int ct = 0; ct < 8; ct++)
            vf[ct] = *(const short8*)&Vs[ct * 16 + ln][quad * 8];

        float4v S[2][2];
#pragma unroll
        for (int qt = 0; qt < 2; qt++)
#pragma unroll
            for (int mh = 0; mh < 2; mh++) S[qt][mh] = (float4v){0.f, 0.f, 0.f, 0.f};
#pragma unroll
        for (int dc = 0; dc < 4; dc++) {
#pragma unroll
            for (int mh = 0; mh < 2; mh++) {
                short8 kf = *(const short8*)&Ks[mh * 16 + ln][dc * 32 + quad * 8];
#pragma unroll
                for (int qt = 0; qt < 2; qt++)
                    S[qt][mh] = __builtin_amdgcn_mfma_f32_16x16x32_bf16(
                        kf, qfrag[qt][dc], S[qt][mh], 0, 0, 0);
            }
        }

#pragma unroll
        for (int qt = 0; qt < 2; qt++) {
            float mx = S[qt][0][0];
#pragma unroll
            for (int r = 1; r < 4; r++) mx = fmaxf(mx, S[qt][0][r]);
#pragma unroll
            for (int r = 0; r < 4; r++) mx = fmaxf(mx, S[qt][1][r]);
            mx = fmaxf(mx, __shfl_xor(mx, 16));
            mx = fmaxf(mx, __shfl_xor(mx, 32));
            float nm = fmaxf(m_run[qt], mx);
            float al = __expf(m_run[qt] - nm);
            m_run[qt] = nm;
            float ps = 0.f;
            unsigned int pk[2][2];
#pragma unroll
            for (int mh = 0; mh < 2; mh++) {
                float p0 = __expf(S[qt][mh][0] - nm);
                float p1 = __expf(S[qt][mh][1] - nm);
                float p2 = __expf(S[qt][mh][2] - nm);
                float p3 = __expf(S[qt][mh][3] - nm);
                ps += p0 + p1 + p2 + p3;
                pk[mh][0] = (unsigned int)f2bf(p0) | ((unsigned int)f2bf(p1) << 16);
                pk[mh][1] = (unsigned int)f2bf(p2) | ((unsigned int)f2bf(p3) << 16);
            }
            ps += __shfl_xor(ps, 16);
            ps += __shfl_xor(ps, 32);
            l_run[qt] = l_run[qt] * al + ps;
#pragma unroll
            for (int mh = 0; mh < 2; mh++) {
                uint2 wv = {pk[mh][0], pk[mh][1]};
                *(uint2*)&Pt[w][ln][mh * 16 + quad * 4] = wv;
            }
            if (__any(al < 1.0f)) {
#pragma unroll
                for (int ct = 0; ct < 8; ct++)
#pragma unroll
                    for (int r = 0; r < 4; r++) O[qt][ct][r] *= al;
            }
            short8 pf = *(const short8*)&Pt[w][ln][quad * 8];
#pragma unroll
            for (int ct = 0; ct < 8; ct++)
                O[qt][ct] = __builtin_amdgcn_mfma_f32_16x16x32_bf16(
                    vf[ct], pf, O[qt][ct], 0, 0, 0);
        }
    }

#pragma unroll
    for (int qt = 0; qt < 2; qt++) {
        float inv = 1.0f / l_run[qt];
        size_t rowoff = ((size_t)b * N_ + qbase_wg + w * 32 + qt * 16 + ln) * 128;
        unsigned short* yh = YH + rowoff;
        unsigned short* yl = YL + rowoff;
#pragma unroll
        for (int ct = 0; ct < 8; ct++) {
            unsigned short h[4], l[4];
#pragma unroll
            for (int r = 0; r < 4; r++) {
                float v = O[qt][ct][r] * inv;
                h[r] = f2bf(v);
                l[r] = f2bf(v - bf2f(h[r]));
            }
            uint2 H = {(unsigned int)h[0] | ((unsigned int)h[1] << 16),
                       (unsigned int)h[2] | ((unsigned int)h[3] << 16)};
            uint2 L = {(unsigned int)l[0] | ((unsigned int)l[1] << 16),
                       (unsigned int)l[2] | ((unsigned int)l[3] << 16)};
            *(uint2*)&yh[ct * 16 + quad * 4] = H;
            *(uint2*)&yl[ct * 16 + quad * 4] = L;
        }
    }
}

// ---------------- k4: W-conv, split-bf16 MFMA, LDS-staged weights + BN stats
__global__ __launch_bounds__(256) void k4_convw(
    const unsigned short* __restrict__ YH, const unsigned short* __restrict__ YL,
    const unsigned short* __restrict__ wp, const float* __restrict__ wb,
    unsigned short* __restrict__ Y2, float* __restrict__ stats) {
    __shared__ __align__(16) unsigned short lds4[17408];
    unsigned short* Ah = lds4;              // [64][136]
    unsigned short* Al = lds4 + 8704;       // [64][136]
    unsigned short* T  = lds4;              // [64][268] (union)

    int t = threadIdx.x;
    int w = t >> 6;
    int lane = t & 63;
    int ln = lane & 15;
    int quad = lane >> 4;
    int nx = blockIdx.x;
    int o0 = blockIdx.y * 64;
    int b = blockIdx.z;

    const unsigned short* wwh = wp + 196608 + o0 * 128;
    const unsigned short* wwl = wp + 229376 + o0 * 128;
#pragma unroll
    for (int r2 = 0; r2 < 4; r2++) {
        int i = t + 256 * r2;
        int row = i >> 4, col8 = (i & 15) * 8;
        *(uint4*)&Ah[row * 136 + col8] = *(const uint4*)&wwh[row * 128 + col8];
        *(uint4*)&Al[row * 136 + col8] = *(const uint4*)&wwl[row * 128 + col8];
    }
    __syncthreads();

    int n0 = nx * 256 + w * 64;
    const unsigned short* yh = YH + ((size_t)b * N_ + n0) * 128;
    const unsigned short* yl = YL + ((size_t)b * N_ + n0) * 128;

    float4v acc[4][4];
#pragma unroll
    for (int ot = 0; ot < 4; ot++)
#pragma unroll
        for (int nt = 0; nt < 4; nt++) acc[ot][nt] = (float4v){0.f, 0.f, 0.f, 0.f};

#pragma unroll
    for (int kc = 0; kc < 4; kc++) {
        int c0 = kc * 32 + quad * 8;
        short8 bh[4], bl[4];
#pragma unroll
        for (int nt = 0; nt < 4; nt++) {
            bh[nt] = *(const short8*)&yh[(size_t)(nt * 16 + ln) * 128 + c0];
            bl[nt] = *(const short8*)&yl[(size_t)(nt * 16 + ln) * 128 + c0];
        }
#pragma unroll
        for (int ot = 0; ot < 4; ot++) {
            short8 ah = *(const short8*)&Ah[(ot * 16 + ln) * 136 + c0];
            short8 al = *(const short8*)&Al[(ot * 16 + ln) * 136 + c0];
#pragma unroll
            for (int nt = 0; nt < 4; nt++) {
                acc[ot][nt] = __builtin_amdgcn_mfma_f32_16x16x32_bf16(
                    ah, bh[nt], acc[ot][nt], 0, 0, 0);
                acc[ot][nt] = __builtin_amdgcn_mfma_f32_16x16x32_bf16(
                    al, bh[nt], acc[ot][nt], 0, 0, 0);
                acc[ot][nt] = __builtin_amdgcn_mfma_f32_16x16x32_bf16(
                    ah, bl[nt], acc[ot][nt], 0, 0, 0);
            }
        }
    }

    __syncthreads();
#pragma unroll
    for (int ot = 0; ot < 4; ot++) {
        float4 bv = *(const float4*)&wb[o0 + ot * 16 + quad * 4];
        float s1[4] = {0.f, 0.f, 0.f, 0.f};
        float s2[4] = {0.f, 0.f, 0.f, 0.f};
#pragma unroll
        for (int nt = 0; nt < 4; nt++)
#pragma unroll
            for (int r = 0; r < 4; r++) {
                float v = acc[ot][nt][r] + ((const float*)&bv)[r];
                s1[r] += v;
                s2[r] += v * v;
                T[(ot * 16 + quad * 4 + r) * 268 + w * 64 + nt * 16 + ln] = f2bf(v);
            }
#pragma unroll
        for (int d = 1; d < 16; d <<= 1)
#pragma unroll
            for (int r = 0; r < 4; r++) {
                s1[r] += __shfl_xor(s1[r], d);
                s2[r] += __shfl_xor(s2[r], d);
            }
        if (ln == 0) {
#pragma unroll
            for (int r = 0; r < 4; r++) {
                int o = o0 + ot * 16 + quad * 4 + r;
                atomicAdd(&stats[o], s1[r]);
                atomicAdd(&stats[256 + o], s2[r]);
            }
        }
    }
    __syncthreads();

    int o_l = t >> 2, seg = t & 3;
    unsigned short* ob = Y2 + ((size_t)b * C_ + o0 + o_l) * N_ + nx * 256 + seg * 64;
#pragma unroll
    for (int j = 0; j < 8; j++) {
        uint2 lo = *(uint2*)&T[o_l * 268 + seg * 64 + j * 8];
        uint2 hi = *(uint2*)&T[o_l * 268 + seg * 64 + j * 8 + 4];
        uint4 v = {lo.x, lo.y, hi.x, hi.y};
        *(uint4*)&ob[j * 8] = v;
    }
}

// ---------------- k6: BN + affine + residual (Y2 bf16 in, fp32 out)
__global__ void k6_bn(const unsigned short* __restrict__ Y2,
                      const float* __restrict__ x,
                      const float* __restrict__ stats,
                      const float* __restrict__ gamma, const float* __restrict__ beta,
                      float* __restrict__ outp) {
    int idx = blockIdx.x * 256 + threadIdx.x;
    size_t base = (size_t)idx * 8;
    int o = (int)((base >> 12) & 255);
    const float cnt = (float)(B_ * N_);
    float mean = stats[o] / cnt;
    float var = stats[256 + o] / cnt - mean * mean;
    float scale = gamma[o] * rsqrtf(var + EPS_BN);
    float shift = beta[o] - mean * scale;
    uint4 yv = *(const uint4*)&Y2[base];
    const unsigned int* yw = &yv.x;
    float4 x0 = *(const float4*)&x[base];
    float4 x1 = *(const float4*)&x[base + 4];
    float y[8];
#pragma unroll
    for (int j = 0; j < 4; j++) {
        y[2 * j] = bf2f((unsigned short)(yw[j] & 0xffff));
        y[2 * j + 1] = bf2f((unsigned short)(yw[j] >> 16));
    }
    float4 o0 = {y[0] * scale + shift + x0.x, y[1] * scale + shift + x0.y,
                 y[2] * scale + shift + x0.z, y[3] * scale + shift + x0.w};
    float4 o1 = {y[4] * scale + shift + x1.x, y[5] * scale + shift + x1.y,
                 y[6] * scale + shift + x1.z, y[7] * scale + shift + x1.w};
    *(float4*)&outp[base] = o0;
    *(float4*)&outp[base + 4] = o1;
}

extern "C" void kernel_launch(void* const* d_in, const int* in_sizes, int n_in,
                              void* d_out, int out_size, void* d_ws, size_t ws_size,
                              hipStream_t stream) {
    const float* x    = (const float*)d_in[0];
    const float* g_w  = (const float*)d_in[1];
    const float* g_b  = (const float*)d_in[2];
    const float* th_w = (const float*)d_in[3];
    const float* th_b = (const float*)d_in[4];
    const float* ph_w = (const float*)d_in[5];
    const float* ph_b = (const float*)d_in[6];
    const float* w_w  = (const float*)d_in[7];
    const float* w_b  = (const float*)d_in[8];
    const float* gam  = (const float*)d_in[9];
    const float* bet  = (const float*)d_in[10];

    char* ws = (char*)d_ws;
    unsigned short* wp  = (unsigned short*)(ws + OFF_W);
    unsigned short* XH  = (unsigned short*)(ws + OFF_XH);
    unsigned short* XL  = (unsigned short*)(ws + OFF_XL);
    unsigned short* Qb  = (unsigned short*)(ws + OFF_Q);
    unsigned short* PHI = (unsigned short*)(ws + OFF_PHI);
    unsigned short* Gb  = (unsigned short*)(ws + OFF_G);
    unsigned short* Kp  = (unsigned short*)(ws + OFF_KP);
    unsigned short* Vt  = (unsigned short*)(ws + OFF_VT);
    unsigned short* YHp = (unsigned short*)(ws + OFF_YH);
    unsigned short* YLp = (unsigned short*)(ws + OFF_YL);
    unsigned short* Y2  = (unsigned short*)(ws + OFF_Y2);
    float*          ST  = (float*)(ws + OFF_ST);
    float* outp = (float*)d_out;

    hipMemsetAsync(ST, 0, 512 * sizeof(float), stream);
    kW_split<<<512, 256, 0, stream>>>(th_w, ph_w, g_w, w_w, wp);
    kX_transpose<<<dim3(64, 4, 16), 256, 0, stream>>>(x, XH, XL);
    k1_proj<<<dim3(16, 2, 48), 256, 0, stream>>>(XH, XL, wp, th_b, ph_b, g_b,
                                                 Qb, PHI, Gb);
    k2k_pool<<<1024, 256, 0, stream>>>(PHI, Kp);
    k2v_poolT<<<dim3(16, 16), 256, 0, stream>>>(Gb, Vt);
    k3_attn<<<dim3(32, 16), 256, 0, stream>>>(Qb, Kp, Vt, YHp, YLp);
    k4_convw<<<dim3(16, 4, 16), 256, 0, stream>>>(YHp, YLp, wp, w_b, Y2, ST);
    k6_bn<<<8192, 256, 0, stream>>>(Y2, x, ST, gam, bet, outp);
}